// Round 9
// baseline (365.513 us; speedup 1.0000x reference)
//
#include <hip/hip_runtime.h>

// ============================================================================
// ActorModel fused inference, MI355X (gfx950)
//
// Math restructuring (exact w.r.t. the reference up to fp rounding):
//   h0 == 0, c0 == 0 (fixed zero inputs)  =>  Whh term and f-gate vanish.
//   gates = [wave|wait|neigh][B,72] @ Wf.T + bias_f     (branch Linears folded)
//   i,o rows pre-scaled by -log2e ; g rows by +2*log2e  (activations -> exp2)
//   c = sig(i)*tanh(g) = (Eg-1) / ((1+Ei)(1+Eg)),  Ei=2^i', Eg=2^g'
//   h = sig(o)*tanh(c) = (Ec-1) / ((1+Eo)(1+Ec)),  Ec=2^(2c*log2e)
//   out = softmax(h @ Wout.T + bout)
//
// R9 = R8 resubmitted verbatim (R8 never ran: GPU acquisition timeout).
// Discriminating experiment: dur_us is dominated by harness poison fills
// (top-5 all fillBufferAligned, 83us each). R6->R7 showed higher-LDS-traffic
// config was FASTER => LDS not binding; lockstep/barrier overhead was. This
// kernel removes the LDS double-buffer entirely (Common-mistake #7: the 10KB
// Wf tile is L1/L2-resident; 4 blocks/CU re-read it with L1 hits). Zero
// intra-loop barriers -> free-running waves -> cross-wave MFMA/VALU/trans
// overlap. Decision rule: |d dur| <= 8us vs 327.3 => reset floor confirmed
// => ROOFLINE next round; d ~= -40us => lockstep theory confirmed.
//
// Precision: fp16 operands; measured absmax 9.8e-4 (passed). f16 MFMA == bf16.
// ============================================================================

#define LOG2E 1.4426950408889634f

typedef _Float16 half8v __attribute__((ext_vector_type(8)));
typedef _Float16 half4v __attribute__((ext_vector_type(4)));
typedef float float4v __attribute__((ext_vector_type(4)));

#if defined(__has_builtin)
#  if __has_builtin(__builtin_amdgcn_mfma_f32_16x16x16f16)
#    define MFMA16(a, b, c) __builtin_amdgcn_mfma_f32_16x16x16f16(a, b, c, 0, 0, 0)
#  elif __has_builtin(__builtin_amdgcn_mfma_f32_16x16x16_f16)
#    define MFMA16(a, b, c) __builtin_amdgcn_mfma_f32_16x16x16_f16(a, b, c, 0, 0, 0)
#  else
#    define MFMA16(a, b, c) __builtin_amdgcn_mfma_f32_16x16x16f16(a, b, c, 0, 0, 0)
#  endif
#  if __has_builtin(__builtin_amdgcn_exp2f)
#    define EXP2(x) __builtin_amdgcn_exp2f(x)
#  else
#    define EXP2(x) __builtin_exp2f(x)
#  endif
#  if __has_builtin(__builtin_amdgcn_rcpf)
#    define RCP(x) __builtin_amdgcn_rcpf(x)
#  else
#    define RCP(x) (1.0f / (x))
#  endif
#else
#  define MFMA16(a, b, c) __builtin_amdgcn_mfma_f32_16x16x16f16(a, b, c, 0, 0, 0)
#  define EXP2(x) __builtin_exp2f(x)
#  define RCP(x) (1.0f / (x))
#endif

__device__ __forceinline__ unsigned short f2h(float x) {
  return __builtin_bit_cast(unsigned short, (_Float16)x);
}

// ---------------------------------------------------------------------------
// Wf layout: [35 ntile][10240 B tile]; tile = [3 gate][16 unit][104 f16 (k,
// 96 used + 8 pad)] + 256 B tail pad  => 640 uint4 / tile.
// Blocks 0..629: Wf fold. Blocks 630..636: biasF. Block 637: WoutF frags.
// ---------------------------------------------------------------------------
__global__ void prep_wb(const float* __restrict__ Wih, const float* __restrict__ W1,
                        const float* __restrict__ W2, const float* __restrict__ W3,
                        const float* __restrict__ b1, const float* __restrict__ b2,
                        const float* __restrict__ b3, const float* __restrict__ bih,
                        const float* __restrict__ bhh, const float* __restrict__ Wout,
                        unsigned short* __restrict__ Wf, float* __restrict__ biasF,
                        uint2* __restrict__ WoutF) {
  if (blockIdx.x < 630) {
    int idx = blockIdx.x * 256 + threadIdx.x;        // 3*560*96 = 161280 exact
    int k = idx % 96;
    int u = (idx / 96) % 560;
    int t = idx / (96 * 560);                        // 0:i 1:g 2:o
    float val = 0.f;
    if (u < 548 && k < 72) {
      int row = u + (t == 0 ? 0 : (t == 1 ? 1096 : 1644));
      const float* wr = Wih + (size_t)row * 224;
      float s = 0.f;
      if (k < 12) {
        #pragma unroll 16
        for (int m = 0; m < 128; ++m) s += wr[m] * W1[m * 12 + k];
      } else if (k < 24) {
        int kk = k - 12;
        #pragma unroll 16
        for (int m = 0; m < 32; ++m) s += wr[128 + m] * W2[m * 12 + kk];
      } else {
        int kk = k - 24;
        #pragma unroll 16
        for (int m = 0; m < 64; ++m) s += wr[160 + m] * W3[m * 48 + kk];
      }
      val = s * (t == 1 ? 2.f * LOG2E : -LOG2E);
    }
    size_t off = (size_t)(u >> 4) * 5120 + (size_t)t * 1664 + (size_t)(u & 15) * 104 + k;
    Wf[off] = f2h(val);
  } else if (blockIdx.x < 637) {
    int idx = (blockIdx.x - 630) * 256 + threadIdx.x;
    if (idx >= 1680) return;
    int u = idx % 560, t = idx / 560;
    float val = 0.f;
    if (u < 548) {
      int row = u + (t == 0 ? 0 : (t == 1 ? 1096 : 1644));
      const float* wr = Wih + (size_t)row * 224;
      float s = bih[row] + bhh[row];
      #pragma unroll 16
      for (int m = 0; m < 128; ++m) s += wr[m] * b1[m];
      #pragma unroll 16
      for (int m = 0; m < 32; ++m) s += wr[128 + m] * b2[m];
      #pragma unroll 16
      for (int m = 0; m < 64; ++m) s += wr[160 + m] * b3[m];
      val = s * (t == 1 ? 2.f * LOG2E : -LOG2E);
    }
    biasF[t * 560 + u] = val;                        // pad units exact 0 -> h=0
  } else {
    // Wout in 16x16x16 A-frag order: entry (t,l): row p=l&15, k=t*16+(l>>4)*4+j
    for (int idx = threadIdx.x; idx < 35 * 64; idx += 256) {
      const int t = idx >> 6, l = idx & 63;
      const int p = l & 15, g = l >> 4;
      half4v w4;
      #pragma unroll
      for (int j = 0; j < 4; ++j) {
        const int u = t * 16 + g * 4 + j;
        const float v = (p < 8 && u < 548) ? Wout[p * 548 + u] : 0.f;
        w4[j] = (_Float16)v;
      }
      WoutF[idx] = __builtin_bit_cast(uint2, w4);
    }
  }
}

// ---------------------------------------------------------------------------
__global__ __launch_bounds__(256, 3) void fused_main(
    const float* __restrict__ wv, const float* __restrict__ wt,
    const float* __restrict__ ng, const char* __restrict__ WfB,
    const float* __restrict__ biasF, const uint2* __restrict__ WoutF,
    const float* __restrict__ bout, float* __restrict__ out) {
  __shared__ __attribute__((aligned(16))) float sBias[1680];          // 6720 B
  __shared__ __attribute__((aligned(16))) _Float16 sX[64 * 80 + 16];  // 10272 B
  // 17 KB LDS, no intra-loop barriers: waves free-run; the 10 KB Wf tile is
  // read straight from L1/L2 each iteration (it's cache-resident by design).

  const int tid = threadIdx.x;
  const int wvi = tid >> 6, lane = tid & 63;
  const int l15 = lane & 15, grp = lane >> 4;
  const int bb0 = blockIdx.x * 64;                   // block's first batch

  // ---- stage this block's inputs f32 -> f16 LDS: sX[blk_batch][k<80] ----
  for (int i = tid; i < 768; i += 256)               // wave: k 0..11
    sX[(i / 12) * 80 + (i % 12)] = (_Float16)wv[(size_t)bb0 * 12 + i];
  for (int i = tid; i < 768; i += 256)               // wait: k 12..23
    sX[(i / 12) * 80 + 12 + (i % 12)] = (_Float16)wt[(size_t)bb0 * 12 + i];
  for (int i = tid; i < 3072; i += 256)              // neigh: k 24..71
    sX[(i / 48) * 80 + 24 + (i % 48)] = (_Float16)ng[(size_t)bb0 * 48 + i];
  for (int i = tid; i < 512; i += 256)               // pad: k 72..79
    sX[(i >> 3) * 80 + 72 + (i & 7)] = (_Float16)0.f;
  if (tid < 16) sX[64 * 80 + tid] = (_Float16)0.f;   // zeroed tail (OOB guard)

  for (int i = tid; i < 1680; i += 256) sBias[i] = biasF[i];
  __syncthreads();                                   // the ONLY barrier

  // X B-fragments from sX: lane=(k_grp<<4)|batch, k = kc*32 + grp*8 + j.
  // kc=2,grp>=2 intentionally overlaps the next row (Wf k>=72 is exact zero,
  // 0*finite=0); last row is backed by the zero tail.
  half8v xfrag[3];
  const int bl = wvi * 16 + l15;
  #pragma unroll
  for (int kc = 0; kc < 3; ++kc)
    xfrag[kc] = *(const half8v*)&sX[bl * 80 + kc * 32 + grp * 8];

  // per-lane Wf fragment base (constant across t; t adds 10240 B)
  const char* wfp = WfB + (size_t)l15 * 208 + (size_t)grp * 16;

  float4v acc2 = {0.f, 0.f, 0.f, 0.f};               // logits^T

  for (int t = 0; t < 35; ++t) {
    const char* base = wfp + (size_t)t * 10240;
    half8v bw[3][3];                                 // W A-fragments, L1/L2 hit
    #pragma unroll
    for (int g3 = 0; g3 < 3; ++g3)
      #pragma unroll
      for (int kc = 0; kc < 3; ++kc)
        bw[g3][kc] = *(const half8v*)(base + g3 * 3328 + kc * 64);
    const uint2 a2w = WoutF[t * 64 + lane];          // L2-resident

    // bias for units t*16+grp*4 .. +3, per gate
    float4v acc[3];
    #pragma unroll
    for (int g3 = 0; g3 < 3; ++g3)
      acc[g3] = *(const float4v*)&sBias[g3 * 560 + t * 16 + grp * 4];

    // gates^T: D[unit = grp*4+r][batch = l15]
    #pragma unroll
    for (int kc = 0; kc < 3; ++kc)
      #pragma unroll
      for (int g3 = 0; g3 < 3; ++g3)
        acc[g3] = __builtin_amdgcn_mfma_f32_16x16x32_f16(
            bw[g3][kc], xfrag[kc], acc[g3], 0, 0, 0);

    // ---- batched activation: independent trans ops grouped for pipe ILP ----
    float Ei[4], Eg[4], Eo[4];                       // pass 1: 12 exp2
    #pragma unroll
    for (int r = 0; r < 4; ++r) {
      Ei[r] = EXP2(acc[0][r]);                       // e^{-i}
      Eg[r] = EXP2(acc[1][r]);                       // e^{2g}
      Eo[r] = EXP2(acc[2][r]);                       // e^{-o}
    }
    float c2[4];                                     // pass 2: 4 rcp
    #pragma unroll
    for (int r = 0; r < 4; ++r) {
      const float den = (1.f + Ei[r]) * (1.f + Eg[r]);
      const float num = __builtin_fmaf(Eg[r], 2.f * LOG2E, -2.f * LOG2E);
      c2[r] = num * RCP(den);                        // = 2*log2e * c
    }
    float Ec[4];                                     // pass 3: 4 exp2
    #pragma unroll
    for (int r = 0; r < 4; ++r) Ec[r] = EXP2(c2[r]);
    half4v hh;                                       // pass 4: 4 rcp -> h
    #pragma unroll
    for (int r = 0; r < 4; ++r) {
      const float den = (1.f + Eo[r]) * (1.f + Ec[r]);
      hh[r] = (_Float16)((Ec[r] - 1.f) * RCP(den));
    }

    const half4v a2 = __builtin_bit_cast(half4v, a2w);
    acc2 = MFMA16(a2, hh, acc2);                     // logits^T[p][b] +=
  }

  // Epilogue: lane (grp<2, b=l15) holds logits[p = grp*4+r][bb0+wvi*16+b]
  if (grp < 2) {
    const float4v bo4 = *(const float4v*)(bout + grp * 4);
    float l[4];
    #pragma unroll
    for (int r = 0; r < 4; ++r) l[r] = acc2[r] + bo4[r];
    float mymax = fmaxf(fmaxf(l[0], l[1]), fmaxf(l[2], l[3]));
    const float mx = fmaxf(mymax, __shfl_xor(mymax, 16, 64));
    float e[4], s = 0.f;
    #pragma unroll
    for (int r = 0; r < 4; ++r) {
      e[r] = EXP2((l[r] - mx) * LOG2E);
      s += e[r];
    }
    s += __shfl_xor(s, 16, 64);
    const float rs = RCP(s);
    float4v res;
    #pragma unroll
    for (int r = 0; r < 4; ++r) res[r] = e[r] * rs;
    const int batch = bb0 + wvi * 16 + l15;
    *(float4v*)(out + (size_t)batch * 8 + grp * 4) = res;
  }
}

// ---------------------------------------------------------------------------
extern "C" void kernel_launch(void* const* d_in, const int* in_sizes, int n_in,
                              void* d_out, int out_size, void* d_ws, size_t ws_size,
                              hipStream_t stream) {
  const float* wave  = (const float*)d_in[0];
  const float* wait_ = (const float*)d_in[1];
  const float* neigh = (const float*)d_in[2];
  const float* W1    = (const float*)d_in[3];
  const float* b1    = (const float*)d_in[4];
  const float* W2    = (const float*)d_in[5];
  const float* b2    = (const float*)d_in[6];
  const float* W3    = (const float*)d_in[7];
  const float* b3    = (const float*)d_in[8];
  const float* Wih   = (const float*)d_in[9];
  // d_in[10] = Whh  (unused: h0 == 0)
  const float* bih   = (const float*)d_in[11];
  const float* bhh   = (const float*)d_in[12];
  const float* Wout  = (const float*)d_in[13];
  const float* bout  = (const float*)d_in[14];
  // d_in[15] = h0, d_in[16] = c0 (zero, unused)
  float* out = (float*)d_out;

  char* ws = (char*)d_ws;
  unsigned short* Wf = (unsigned short*)(ws);        //      0 .. 358400
  float* biasF = (float*)(ws + 358400);              // 358400 .. 365120
  uint2* WoutF = (uint2*)(ws + 365120);              // 365120 .. 383040 (383 KB total)

  hipLaunchKernelGGL(prep_wb, dim3(638), dim3(256), 0, stream,
                     Wih, W1, W2, W3, b1, b2, b3, bih, bhh, Wout, Wf, biasF, WoutF);
  hipLaunchKernelGGL(fused_main, dim3(1024), dim3(256), 0, stream,
                     wave, wait_, neigh, (const char*)Wf, biasF, WoutF, bout, out);
}

// Round 10
// 326.793 us; speedup vs baseline: 1.1185x; 1.1185x over previous
//
#include <hip/hip_runtime.h>

// ============================================================================
// ActorModel fused inference, MI355X (gfx950)
//
// Math restructuring (exact w.r.t. the reference up to fp rounding):
//   h0 == 0, c0 == 0 (fixed zero inputs)  =>  Whh term and f-gate vanish.
//   gates = [wave|wait|neigh][B,72] @ Wf.T + bias_f     (branch Linears folded)
//   i,o rows pre-scaled by -log2e ; g rows by +2*log2e  (activations -> exp2)
//   c = sig(i)*tanh(g) = (Eg-1) / ((1+Ei)(1+Eg)),  Ei=2^i', Eg=2^g'
//   h = sig(o)*tanh(c) = (Ec-1) / ((1+Eo)(1+Ec)),  Ec=2^(2c*log2e)
//   out = softmax(h @ Wout.T + bout)
//
// R10: R9 gave first per-kernel counters: fused_main 98.8us, MfmaUtil 9%,
// VALUBusy 24%, HBM 2%, occ 38% -> LATENCY-bound on the per-iter 9-load ->
// vmcnt -> MFMA chain (Wf stream 358KB doesn't fit L1; L2 lat ~200-400cy).
// Fix: WEIGHT-STATIONARY waves. Each wave owns ~9 ntiles; per ntile it loads
// weights ONCE (13 loads) and reuses them over 4 batch-tiles whose X-frags
// sit in registers (loaded once from LDS). Per batch-tile iteration has ZERO
// memory dependency; 4 independent MFMA->activation streams give ILP. Wave
// partial logits reduced across the block via 16KB LDS + 1 barrier.
// Predicted: fused_main 20-35us (trans-pipe floor ~11us + overheads),
// VALUBusy 45-65%, MfmaUtil 15-25%. Total ~285-305 (harness fills ~250us).
//
// Precision: fp16 operands; measured absmax 9.8e-4 (passed). f16 MFMA == bf16.
// ============================================================================

#define LOG2E 1.4426950408889634f

typedef _Float16 half8v __attribute__((ext_vector_type(8)));
typedef _Float16 half4v __attribute__((ext_vector_type(4)));
typedef float float4v __attribute__((ext_vector_type(4)));

#if defined(__has_builtin)
#  if __has_builtin(__builtin_amdgcn_mfma_f32_16x16x16f16)
#    define MFMA16(a, b, c) __builtin_amdgcn_mfma_f32_16x16x16f16(a, b, c, 0, 0, 0)
#  elif __has_builtin(__builtin_amdgcn_mfma_f32_16x16x16_f16)
#    define MFMA16(a, b, c) __builtin_amdgcn_mfma_f32_16x16x16_f16(a, b, c, 0, 0, 0)
#  else
#    define MFMA16(a, b, c) __builtin_amdgcn_mfma_f32_16x16x16f16(a, b, c, 0, 0, 0)
#  endif
#  if __has_builtin(__builtin_amdgcn_exp2f)
#    define EXP2(x) __builtin_amdgcn_exp2f(x)
#  else
#    define EXP2(x) __builtin_exp2f(x)
#  endif
#  if __has_builtin(__builtin_amdgcn_rcpf)
#    define RCP(x) __builtin_amdgcn_rcpf(x)
#  else
#    define RCP(x) (1.0f / (x))
#  endif
#else
#  define MFMA16(a, b, c) __builtin_amdgcn_mfma_f32_16x16x16f16(a, b, c, 0, 0, 0)
#  define EXP2(x) __builtin_exp2f(x)
#  define RCP(x) (1.0f / (x))
#endif

__device__ __forceinline__ unsigned short f2h(float x) {
  return __builtin_bit_cast(unsigned short, (_Float16)x);
}

// ---------------------------------------------------------------------------
// Wf layout: [35 ntile][10240 B tile]; tile = [3 gate][16 unit][104 f16 (k,
// 96 used + 8 pad)] + 256 B tail pad  => 640 uint4 / tile.
// Blocks 0..629: Wf fold. Blocks 630..636: biasF. Block 637: WoutF frags.
// ---------------------------------------------------------------------------
__global__ void prep_wb(const float* __restrict__ Wih, const float* __restrict__ W1,
                        const float* __restrict__ W2, const float* __restrict__ W3,
                        const float* __restrict__ b1, const float* __restrict__ b2,
                        const float* __restrict__ b3, const float* __restrict__ bih,
                        const float* __restrict__ bhh, const float* __restrict__ Wout,
                        unsigned short* __restrict__ Wf, float* __restrict__ biasF,
                        uint2* __restrict__ WoutF) {
  if (blockIdx.x < 630) {
    int idx = blockIdx.x * 256 + threadIdx.x;        // 3*560*96 = 161280 exact
    int k = idx % 96;
    int u = (idx / 96) % 560;
    int t = idx / (96 * 560);                        // 0:i 1:g 2:o
    float val = 0.f;
    if (u < 548 && k < 72) {
      int row = u + (t == 0 ? 0 : (t == 1 ? 1096 : 1644));
      const float* wr = Wih + (size_t)row * 224;
      float s = 0.f;
      if (k < 12) {
        #pragma unroll 16
        for (int m = 0; m < 128; ++m) s += wr[m] * W1[m * 12 + k];
      } else if (k < 24) {
        int kk = k - 12;
        #pragma unroll 16
        for (int m = 0; m < 32; ++m) s += wr[128 + m] * W2[m * 12 + kk];
      } else {
        int kk = k - 24;
        #pragma unroll 16
        for (int m = 0; m < 64; ++m) s += wr[160 + m] * W3[m * 48 + kk];
      }
      val = s * (t == 1 ? 2.f * LOG2E : -LOG2E);
    }
    size_t off = (size_t)(u >> 4) * 5120 + (size_t)t * 1664 + (size_t)(u & 15) * 104 + k;
    Wf[off] = f2h(val);
  } else if (blockIdx.x < 637) {
    int idx = (blockIdx.x - 630) * 256 + threadIdx.x;
    if (idx >= 1680) return;
    int u = idx % 560, t = idx / 560;
    float val = 0.f;
    if (u < 548) {
      int row = u + (t == 0 ? 0 : (t == 1 ? 1096 : 1644));
      const float* wr = Wih + (size_t)row * 224;
      float s = bih[row] + bhh[row];
      #pragma unroll 16
      for (int m = 0; m < 128; ++m) s += wr[m] * b1[m];
      #pragma unroll 16
      for (int m = 0; m < 32; ++m) s += wr[128 + m] * b2[m];
      #pragma unroll 16
      for (int m = 0; m < 64; ++m) s += wr[160 + m] * b3[m];
      val = s * (t == 1 ? 2.f * LOG2E : -LOG2E);
    }
    biasF[t * 560 + u] = val;                        // pad units exact 0 -> h=0
  } else {
    // Wout in 16x16x16 A-frag order: entry (t,l): row p=l&15, k=t*16+(l>>4)*4+j
    for (int idx = threadIdx.x; idx < 35 * 64; idx += 256) {
      const int t = idx >> 6, l = idx & 63;
      const int p = l & 15, g = l >> 4;
      half4v w4;
      #pragma unroll
      for (int j = 0; j < 4; ++j) {
        const int u = t * 16 + g * 4 + j;
        const float v = (p < 8 && u < 548) ? Wout[p * 548 + u] : 0.f;
        w4[j] = (_Float16)v;
      }
      WoutF[idx] = __builtin_bit_cast(uint2, w4);
    }
  }
}

// ---------------------------------------------------------------------------
__global__ __launch_bounds__(256, 3) void fused_main(
    const float* __restrict__ wv, const float* __restrict__ wt,
    const float* __restrict__ ng, const char* __restrict__ WfB,
    const float* __restrict__ biasF, const uint2* __restrict__ WoutF,
    const float* __restrict__ bout, float* __restrict__ out) {
  __shared__ __attribute__((aligned(16))) _Float16 sX[64 * 80 + 16];  // 10272 B
  __shared__ __attribute__((aligned(16))) float4v sRed[4][4][64];     // 16384 B

  const int tid = threadIdx.x;
  const int wvi = tid >> 6, lane = tid & 63;
  const int l15 = lane & 15, grp = lane >> 4;
  const int bb0 = blockIdx.x * 64;                   // block's first batch

  // ---- stage this block's inputs f32 -> f16 LDS: sX[blk_batch][k<80] ----
  for (int i = tid; i < 768; i += 256)               // wave: k 0..11
    sX[(i / 12) * 80 + (i % 12)] = (_Float16)wv[(size_t)bb0 * 12 + i];
  for (int i = tid; i < 768; i += 256)               // wait: k 12..23
    sX[(i / 12) * 80 + 12 + (i % 12)] = (_Float16)wt[(size_t)bb0 * 12 + i];
  for (int i = tid; i < 3072; i += 256)              // neigh: k 24..71
    sX[(i / 48) * 80 + 24 + (i % 48)] = (_Float16)ng[(size_t)bb0 * 48 + i];
  for (int i = tid; i < 512; i += 256)               // pad: k 72..79
    sX[(i >> 3) * 80 + 72 + (i & 7)] = (_Float16)0.f;
  if (tid < 16) sX[64 * 80 + tid] = (_Float16)0.f;   // zeroed tail (OOB guard)
  __syncthreads();

  // X B-fragments for ALL 4 batch-tiles, held in registers (48 VGPR).
  // lane=(k_grp<<4)|batch, k = kc*32 + grp*8 + j. kc=2,grp>=2 intentionally
  // overlaps the next row (Wf k>=72 is exact zero, 0*finite=0); the last row
  // is backed by the zero tail.
  half8v xf[4][3];
  #pragma unroll
  for (int bt = 0; bt < 4; ++bt)
    #pragma unroll
    for (int kc = 0; kc < 3; ++kc)
      xf[bt][kc] = *(const half8v*)&sX[(bt * 16 + l15) * 80 + kc * 32 + grp * 8];

  // Weight-stationary: wave wvi owns ntiles [n0, n0+cnt)
  const int n0 = wvi ? 9 * wvi - 1 : 0;              // 0:8 | 8..16 | 17..25 | 26..34
  const int cnt = wvi ? 9 : 8;

  float4v acc2[4] = {{0.f, 0.f, 0.f, 0.f}, {0.f, 0.f, 0.f, 0.f},
                     {0.f, 0.f, 0.f, 0.f}, {0.f, 0.f, 0.f, 0.f}};  // logits^T

  const char* wfp = WfB + (size_t)l15 * 208 + (size_t)grp * 16;

  for (int j = 0; j < cnt; ++j) {
    const int t = n0 + j;
    // ---- per-ntile loads: issued ONCE, reused over 4 batch-tiles ----
    const char* base = wfp + (size_t)t * 10240;
    half8v bw[3][3];                                 // W A-fragments (36 VGPR)
    #pragma unroll
    for (int g3 = 0; g3 < 3; ++g3)
      #pragma unroll
      for (int kc = 0; kc < 3; ++kc)
        bw[g3][kc] = *(const half8v*)(base + g3 * 3328 + kc * 64);
    const uint2 a2w = WoutF[t * 64 + lane];
    float4v bi[3];                                   // bias (L2-resident)
    #pragma unroll
    for (int g3 = 0; g3 < 3; ++g3)
      bi[g3] = *(const float4v*)(biasF + g3 * 560 + t * 16 + grp * 4);
    const half4v a2 = __builtin_bit_cast(half4v, a2w);

    #pragma unroll
    for (int bt = 0; bt < 4; ++bt) {                 // 4 independent streams
      float4v acc[3];
      #pragma unroll
      for (int g3 = 0; g3 < 3; ++g3) acc[g3] = bi[g3];
      // gates^T: D[unit = grp*4+r][batch = l15]
      #pragma unroll
      for (int kc = 0; kc < 3; ++kc)
        #pragma unroll
        for (int g3 = 0; g3 < 3; ++g3)
          acc[g3] = __builtin_amdgcn_mfma_f32_16x16x32_f16(
              bw[g3][kc], xf[bt][kc], acc[g3], 0, 0, 0);

      // ---- batched activation (trans ops grouped for pipe ILP) ----
      float Ei[4], Eg[4], Eo[4];
      #pragma unroll
      for (int r = 0; r < 4; ++r) {
        Ei[r] = EXP2(acc[0][r]);                     // e^{-i}
        Eg[r] = EXP2(acc[1][r]);                     // e^{2g}
        Eo[r] = EXP2(acc[2][r]);                     // e^{-o}
      }
      float c2[4];
      #pragma unroll
      for (int r = 0; r < 4; ++r) {
        const float den = (1.f + Ei[r]) * (1.f + Eg[r]);
        const float num = __builtin_fmaf(Eg[r], 2.f * LOG2E, -2.f * LOG2E);
        c2[r] = num * RCP(den);                      // = 2*log2e * c
      }
      float Ec[4];
      #pragma unroll
      for (int r = 0; r < 4; ++r) Ec[r] = EXP2(c2[r]);
      half4v hh;
      #pragma unroll
      for (int r = 0; r < 4; ++r) {
        const float den = (1.f + Eo[r]) * (1.f + Ec[r]);
        hh[r] = (_Float16)((Ec[r] - 1.f) * RCP(den));
      }
      acc2[bt] = MFMA16(a2, hh, acc2[bt]);           // logits^T[p][b] +=
    }
  }

  // ---- cross-wave reduction of partial logits ----
  #pragma unroll
  for (int bt = 0; bt < 4; ++bt) sRed[wvi][bt][lane] = acc2[bt];
  __syncthreads();

  // wave wvi finishes batch-tile bt = wvi
  const float4v s0 = sRed[0][wvi][lane], s1 = sRed[1][wvi][lane];
  const float4v s2 = sRed[2][wvi][lane], s3 = sRed[3][wvi][lane];
  float4v lg;
  #pragma unroll
  for (int r = 0; r < 4; ++r) lg[r] = (s0[r] + s1[r]) + (s2[r] + s3[r]);

  // lane (grp<2, b=l15) holds logits[p = grp*4+r][bb0 + wvi*16 + b]
  if (grp < 2) {
    const float4v bo4 = *(const float4v*)(bout + grp * 4);
    float l[4];
    #pragma unroll
    for (int r = 0; r < 4; ++r) l[r] = lg[r] + bo4[r];
    float mymax = fmaxf(fmaxf(l[0], l[1]), fmaxf(l[2], l[3]));
    const float mx = fmaxf(mymax, __shfl_xor(mymax, 16, 64));
    float e[4], s = 0.f;
    #pragma unroll
    for (int r = 0; r < 4; ++r) {
      e[r] = EXP2((l[r] - mx) * LOG2E);
      s += e[r];
    }
    s += __shfl_xor(s, 16, 64);
    const float rs = RCP(s);
    float4v res;
    #pragma unroll
    for (int r = 0; r < 4; ++r) res[r] = e[r] * rs;
    const int batch = bb0 + wvi * 16 + l15;
    *(float4v*)(out + (size_t)batch * 8 + grp * 4) = res;
  }
}

// ---------------------------------------------------------------------------
extern "C" void kernel_launch(void* const* d_in, const int* in_sizes, int n_in,
                              void* d_out, int out_size, void* d_ws, size_t ws_size,
                              hipStream_t stream) {
  const float* wave  = (const float*)d_in[0];
  const float* wait_ = (const float*)d_in[1];
  const float* neigh = (const float*)d_in[2];
  const float* W1    = (const float*)d_in[3];
  const float* b1    = (const float*)d_in[4];
  const float* W2    = (const float*)d_in[5];
  const float* b2    = (const float*)d_in[6];
  const float* W3    = (const float*)d_in[7];
  const float* b3    = (const float*)d_in[8];
  const float* Wih   = (const float*)d_in[9];
  // d_in[10] = Whh  (unused: h0 == 0)
  const float* bih   = (const float*)d_in[11];
  const float* bhh   = (const float*)d_in[12];
  const float* Wout  = (const float*)d_in[13];
  const float* bout  = (const float*)d_in[14];
  // d_in[15] = h0, d_in[16] = c0 (zero, unused)
  float* out = (float*)d_out;

  char* ws = (char*)d_ws;
  unsigned short* Wf = (unsigned short*)(ws);        //      0 .. 358400
  float* biasF = (float*)(ws + 358400);              // 358400 .. 365120
  uint2* WoutF = (uint2*)(ws + 365120);              // 365120 .. 383040 (383 KB total)

  hipLaunchKernelGGL(prep_wb, dim3(638), dim3(256), 0, stream,
                     Wih, W1, W2, W3, b1, b2, b3, bih, bhh, Wout, Wf, biasF, WoutF);
  hipLaunchKernelGGL(fused_main, dim3(1024), dim3(256), 0, stream,
                     wave, wait_, neigh, (const char*)Wf, biasF, WoutF, bout, out);
}